// Round 3
// baseline (438.106 us; speedup 1.0000x reference)
//
#include <hip/hip_runtime.h>

// Sparsemax along dim=-1 for x[4,4096,4096] fp32.
// tau solves sum(max(x - tau, 0)) = 1. Newton iteration on convex
// piecewise-linear f(tau) = sum(max(x-tau,0)) - 1:
//   tau <- (sum_{x>tau} x - 1) / count_{x>tau}
// from tau0 = max(x) - 1 (f >= 0 there). Support shrinks monotonically;
// converges finitely (typically ~5-7 iters for Gaussian rows).
//
// Round-2 structure: ONE WAVE PER ROW. 64 lanes x 64 elements in VGPRs.
// No __syncthreads, no LDS: reductions are 6-step __shfl_xor butterflies.
// Butterfly results are bit-identical across lanes (same pair tree each
// level; fp add is commutative), so the uniform `break` is safe.

#define ROW_D 4096
#define BLOCK 256          // 4 waves per block, 1 row per wave
#define NV 16              // float4 per lane: 16*4 = 64 elements/lane

__global__ __launch_bounds__(BLOCK)
void sparsemax_wave_kernel(const float* __restrict__ x,
                           float* __restrict__ out,
                           int nrows) {
    const int wid  = blockIdx.x * (BLOCK / 64) + (threadIdx.x >> 6);
    const int lane = threadIdx.x & 63;
    if (wid >= nrows) return;   // wave-uniform

    const float* __restrict__ xr   = x   + (size_t)wid * ROW_D;
    float* __restrict__       outr = out + (size_t)wid * ROW_D;

    // ---- load 64 elements per lane, coalesced float4 ----
    float4 v[NV];
#pragma unroll
    for (int j = 0; j < NV; ++j)
        v[j] = reinterpret_cast<const float4*>(xr)[lane + j * 64];

    // ---- wave max (register tree + shfl_xor butterfly) ----
    float m = fmaxf(fmaxf(v[0].x, v[0].y), fmaxf(v[0].z, v[0].w));
#pragma unroll
    for (int j = 1; j < NV; ++j)
        m = fmaxf(m, fmaxf(fmaxf(v[j].x, v[j].y), fmaxf(v[j].z, v[j].w)));
#pragma unroll
    for (int off = 1; off < 64; off <<= 1)
        m = fmaxf(m, __shfl_xor(m, off, 64));

    float tau = m - 1.0f;

    // ---- Newton iterations, wave-uniform tau ----
    for (int it = 0; it < 32; ++it) {
        float s = 0.0f, k = 0.0f;
#pragma unroll
        for (int j = 0; j < NV; ++j) {
            float a0 = v[j].x, a1 = v[j].y, a2 = v[j].z, a3 = v[j].w;
            if (a0 > tau) { s += a0; k += 1.0f; }
            if (a1 > tau) { s += a1; k += 1.0f; }
            if (a2 > tau) { s += a2; k += 1.0f; }
            if (a3 > tau) { s += a3; k += 1.0f; }
        }
#pragma unroll
        for (int off = 1; off < 64; off <<= 1) {
            s += __shfl_xor(s, off, 64);
            k += __shfl_xor(k, off, 64);
        }
        float ntau = (s - 1.0f) / k;   // k >= 1 always (max stays in support)
        if (ntau == tau) break;        // bit-exact, wave-uniform
        tau = ntau;
    }

    // ---- output: max(x - tau, 0), coalesced float4 ----
#pragma unroll
    for (int j = 0; j < NV; ++j) {
        float4 o;
        o.x = fmaxf(v[j].x - tau, 0.0f);
        o.y = fmaxf(v[j].y - tau, 0.0f);
        o.z = fmaxf(v[j].z - tau, 0.0f);
        o.w = fmaxf(v[j].w - tau, 0.0f);
        reinterpret_cast<float4*>(outr)[lane + j * 64] = o;
    }
}

extern "C" void kernel_launch(void* const* d_in, const int* in_sizes, int n_in,
                              void* d_out, int out_size, void* d_ws, size_t ws_size,
                              hipStream_t stream) {
    const float* x = (const float*)d_in[0];
    float* out = (float*)d_out;
    const int nrows = in_sizes[0] / ROW_D;            // 16384
    const int nblocks = (nrows + (BLOCK / 64) - 1) / (BLOCK / 64);
    sparsemax_wave_kernel<<<nblocks, BLOCK, 0, stream>>>(x, out, nrows);
}